// Round 1
// baseline (2244.080 us; speedup 1.0000x reference)
//
#include <hip/hip_runtime.h>
#include <hip/hip_bf16.h>
#include <cstddef>

typedef __attribute__((ext_vector_type(8))) short short8;
typedef __attribute__((ext_vector_type(8))) unsigned short u16x8;
typedef __attribute__((ext_vector_type(4))) float f32x4;

__device__ inline unsigned short f2bf(float f) {
    __hip_bfloat16 h = __float2bfloat16(f);
    unsigned short u;
    __builtin_memcpy(&u, &h, sizeof(u));
    return u;
}

// ---------------------------------------------------------------------------
// Pack / transpose / degree kernel: in fp32 [R,C] ->
//   out   : bf16 [R,C]      (optional)
//   outT  : bf16 [C,R] ldT  (optional)
//   rowsum: atomic fp32 [R] (optional)
//   colsum: atomic fp32 [C] (optional)
// grid (C/32, R/32), block (32,8)
// ---------------------------------------------------------------------------
__global__ __launch_bounds__(256)
void pack32(const float* __restrict__ in, int R, int C,
            unsigned short* __restrict__ out,
            unsigned short* __restrict__ outT, int ldT,
            float* __restrict__ rowsum, float* __restrict__ colsum)
{
    __shared__ float t[32][33];
    int c0 = blockIdx.x * 32, r0 = blockIdx.y * 32;
    int tx = threadIdx.x, ty = threadIdx.y;
#pragma unroll
    for (int i = 0; i < 4; i++) {
        int r = ty + i * 8;
        float v = in[(size_t)(r0 + r) * C + c0 + tx];
        t[r][tx] = v;
        if (out) out[(size_t)(r0 + r) * C + c0 + tx] = f2bf(v);
    }
    __syncthreads();
    if (outT) {
#pragma unroll
        for (int i = 0; i < 4; i++) {
            int c = ty + i * 8;
            outT[(size_t)(c0 + c) * ldT + r0 + tx] = f2bf(t[tx][c]);
        }
    }
    if (rowsum && ty == 0) {
        float s = 0.f;
#pragma unroll
        for (int j = 0; j < 32; j++) s += t[tx][j];
        atomicAdd(&rowsum[r0 + tx], s);
    }
    if (colsum && ty == 1) {
        float s = 0.f;
#pragma unroll
        for (int j = 0; j < 32; j++) s += t[j][tx];
        atomicAdd(&colsum[c0 + tx], s);
    }
}

// ---------------------------------------------------------------------------
// GEMM: C[M,N] = A[M,K] * Bt[N,K]^T   (A fp32-on-the-fly or bf16; Bt bf16)
// Tiles: BM=128 BN=64 BK=32, 256 threads (4 waves, each 64x32 via 4x2 MFMA)
// Epilogue modes:
//  0: split  : n<256 -> TB[n*Mld+m]=bf16(v) ; n>=256 -> P2w[m*256+n-256]=v
//  1: edgeT  : s=deg?inv(deg[m]):1 ; TB[n*Mld+m]=bf16(s*v)
//  2: h      : s=inv(deg[m]) ; RB[m*256+n]=bf16(relu(s*v+bias1[n]))
//  3: final  : s=inv(deg[m]) ; out[m*256+n]=0.5*(s*v+bias1[n]+P2r[m*256+n]+bias2[n])
// ---------------------------------------------------------------------------
struct EpiParams {
    int mode;
    const float* deg;
    const float* bias1;
    const float* bias2;
    const float* P2r;
    float* P2w;
    unsigned short* TB;
    unsigned short* RB;
    float* out;
    int Mld;
};

#define TBM 128
#define TBN 64
#define TBK 32
#define LDSK 40

template<bool AF32>
__global__ __launch_bounds__(256)
void gemm_kern(const void* __restrict__ Ap1, const void* __restrict__ Ap2,
               int K1, int lda,
               const unsigned short* __restrict__ Bt, int ldb,
               int M, int N, int K, EpiParams ep)
{
    __shared__ unsigned short Al[TBM][LDSK];
    __shared__ unsigned short Bl[TBN][LDSK];
    int tid = threadIdx.x;
    int l = tid & 63;
    int w = tid >> 6;
    int wm0 = (w >> 1) * 64;
    int wn0 = (w & 1) * 32;
    int m0 = blockIdx.y * TBM;
    int n0 = blockIdx.x * TBN;

    f32x4 acc[4][2] = {};

    int arow = tid >> 1, ahalf = tid & 1;
    int brow = tid >> 2, bq = tid & 3;

    for (int k0 = 0; k0 < K; k0 += TBK) {
        __syncthreads();
        // ---- stage A tile [128][32]
        if (AF32) {
            const float* base;
            int kloc;
            if (k0 < K1) { base = (const float*)Ap1; kloc = k0; }
            else         { base = (const float*)Ap2; kloc = k0 - K1; }
            const float* src = base + (size_t)(m0 + arow) * lda + kloc + ahalf * 16;
            float4 v0 = ((const float4*)src)[0];
            float4 v1 = ((const float4*)src)[1];
            float4 v2 = ((const float4*)src)[2];
            float4 v3 = ((const float4*)src)[3];
            u16x8 p0, p1;
            p0[0] = f2bf(v0.x); p0[1] = f2bf(v0.y); p0[2] = f2bf(v0.z); p0[3] = f2bf(v0.w);
            p0[4] = f2bf(v1.x); p0[5] = f2bf(v1.y); p0[6] = f2bf(v1.z); p0[7] = f2bf(v1.w);
            p1[0] = f2bf(v2.x); p1[1] = f2bf(v2.y); p1[2] = f2bf(v2.z); p1[3] = f2bf(v2.w);
            p1[4] = f2bf(v3.x); p1[5] = f2bf(v3.y); p1[6] = f2bf(v3.z); p1[7] = f2bf(v3.w);
            *(u16x8*)&Al[arow][ahalf * 16]     = p0;
            *(u16x8*)&Al[arow][ahalf * 16 + 8] = p1;
        } else {
            const unsigned short* src =
                (const unsigned short*)Ap1 + (size_t)(m0 + arow) * lda + k0 + ahalf * 16;
            *(u16x8*)&Al[arow][ahalf * 16]     = *(const u16x8*)src;
            *(u16x8*)&Al[arow][ahalf * 16 + 8] = *(const u16x8*)(src + 8);
        }
        // ---- stage B tile [64][32] from Bt [N,K]
        {
            const unsigned short* src = Bt + (size_t)(n0 + brow) * ldb + k0 + bq * 8;
            *(u16x8*)&Bl[brow][bq * 8] = *(const u16x8*)src;
        }
        __syncthreads();
        // ---- compute
        short8 af[4], bfr[2];
        int ko = (l >> 4) * 8;
        int ar = l & 15;
#pragma unroll
        for (int fi = 0; fi < 4; fi++)
            af[fi] = *(const short8*)&Al[wm0 + fi * 16 + ar][ko];
#pragma unroll
        for (int fj = 0; fj < 2; fj++)
            bfr[fj] = *(const short8*)&Bl[wn0 + fj * 16 + ar][ko];
#pragma unroll
        for (int fi = 0; fi < 4; fi++)
#pragma unroll
            for (int fj = 0; fj < 2; fj++)
                acc[fi][fj] = __builtin_amdgcn_mfma_f32_16x16x32_bf16(
                    af[fi], bfr[fj], acc[fi][fj], 0, 0, 0);
    }

    // ---- epilogue
#pragma unroll
    for (int fi = 0; fi < 4; fi++) {
#pragma unroll
        for (int fj = 0; fj < 2; fj++) {
#pragma unroll
            for (int r = 0; r < 4; r++) {
                int m = m0 + wm0 + fi * 16 + ((l >> 4) << 2) + r;
                int n = n0 + wn0 + fj * 16 + (l & 15);
                float v = acc[fi][fj][r];
                if (ep.mode == 0) {
                    if (n < 256) ep.TB[(size_t)n * ep.Mld + m] = f2bf(v);
                    else         ep.P2w[(size_t)m * 256 + (n - 256)] = v;
                } else if (ep.mode == 1) {
                    float s = 1.f;
                    if (ep.deg) { float d = ep.deg[m]; s = d > 0.f ? 1.f / d : 0.f; }
                    ep.TB[(size_t)n * ep.Mld + m] = f2bf(s * v);
                } else if (ep.mode == 2) {
                    float d = ep.deg[m];
                    float s = d > 0.f ? 1.f / d : 0.f;
                    float hv = s * v + ep.bias1[n];
                    ep.RB[(size_t)m * 256 + n] = f2bf(hv > 0.f ? hv : 0.f);
                } else {
                    float d = ep.deg[m];
                    float s = d > 0.f ? 1.f / d : 0.f;
                    ep.out[(size_t)m * 256 + n] =
                        0.5f * (s * v + ep.bias1[n] + ep.P2r[(size_t)m * 256 + n] + ep.bias2[n]);
                }
            }
        }
    }
}

// ---------------------------------------------------------------------------
#define N_RNA 6144
#define N_DIS 4096
#define HID 256

extern "C" void kernel_launch(void* const* d_in, const int* in_sizes, int n_in,
                              void* d_out, int out_size, void* d_ws, size_t ws_size,
                              hipStream_t stream) {
    const float* m_f   = (const float*)d_in[0];
    const float* d_f   = (const float*)d_in[1];
    const float* c_func= (const float*)d_in[2];
    const float* c_gs  = (const float*)d_in[3];
    const float* d_ss  = (const float*)d_in[4];
    const float* dd_g  = (const float*)d_in[5];
    const float* W1m   = (const float*)d_in[6];
    const float* b1m   = (const float*)d_in[7];
    const float* W2m   = (const float*)d_in[8];
    const float* b2m   = (const float*)d_in[9];
    const float* W1d   = (const float*)d_in[10];
    const float* b1d   = (const float*)d_in[11];
    const float* W2d   = (const float*)d_in[12];
    const float* b2d   = (const float*)d_in[13];
    const float* Wm    = (const float*)d_in[14];
    const float* bm    = (const float*)d_in[15];
    const float* Wd    = (const float*)d_in[16];
    const float* bd    = (const float*)d_in[17];
    float* out = (float*)d_out;

    char* ws = (char*)d_ws;
    size_t off = 0;
    auto alloc = [&](size_t bytes) {
        void* p = ws + off;
        off = (off + bytes + 255) & ~(size_t)255;
        return p;
    };

    unsigned short* adjm  = (unsigned short*)alloc((size_t)N_RNA * N_RNA * 2);
    unsigned short* adjmT = (unsigned short*)alloc((size_t)N_RNA * N_RNA * 2);
    unsigned short* adjd  = (unsigned short*)alloc((size_t)N_DIS * N_DIS * 2);
    unsigned short* adjdT = (unsigned short*)alloc((size_t)N_DIS * N_DIS * 2);
    unsigned short* WcatM = (unsigned short*)alloc((size_t)512 * 2 * N_RNA * 2);
    unsigned short* WcatD = (unsigned short*)alloc((size_t)512 * 2 * N_DIS * 2);
    unsigned short* W2mT  = (unsigned short*)alloc((size_t)HID * HID * 2);
    unsigned short* W2dT  = (unsigned short*)alloc((size_t)HID * HID * 2);
    float* degs   = (float*)alloc((size_t)(2 * N_RNA + 2 * N_DIS) * 4);
    float* degEm = degs;
    float* degNm = degs + N_RNA;
    float* degEd = degs + 2 * N_RNA;
    float* degNd = degs + 2 * N_RNA + N_DIS;
    float* P2m = (float*)alloc((size_t)N_RNA * HID * 4);
    float* P2d = (float*)alloc((size_t)N_DIS * HID * 4);
    unsigned short* XwTm  = (unsigned short*)alloc((size_t)HID * N_RNA * 2);
    unsigned short* edTm  = (unsigned short*)alloc((size_t)HID * N_RNA * 2);
    unsigned short* hm    = (unsigned short*)alloc((size_t)N_RNA * HID * 2);
    unsigned short* Xw2Tm = (unsigned short*)alloc((size_t)HID * N_RNA * 2);
    unsigned short* ed2Tm = (unsigned short*)alloc((size_t)HID * N_RNA * 2);
    unsigned short* XwTd  = (unsigned short*)alloc((size_t)HID * N_DIS * 2);
    unsigned short* edTd  = (unsigned short*)alloc((size_t)HID * N_DIS * 2);
    unsigned short* hd    = (unsigned short*)alloc((size_t)N_DIS * HID * 2);
    unsigned short* Xw2Td = (unsigned short*)alloc((size_t)HID * N_DIS * 2);
    unsigned short* ed2Td = (unsigned short*)alloc((size_t)HID * N_DIS * 2);

    hipMemsetAsync(degs, 0, (size_t)(2 * N_RNA + 2 * N_DIS) * 4, stream);

    dim3 bp(32, 8);
    // adjacency pack + transpose + degrees
    pack32<<<dim3(N_RNA / 32, N_RNA / 32), bp, 0, stream>>>(
        m_f, N_RNA, N_RNA, adjm, adjmT, N_RNA, degEm, degNm);
    pack32<<<dim3(N_DIS / 32, N_DIS / 32), bp, 0, stream>>>(
        d_f, N_DIS, N_DIS, adjd, adjdT, N_DIS, degEd, degNd);
    // weights: Wcat rows 0..255 = W1^T, rows 256..511 = Wshort (already [HID, 2N])
    pack32<<<dim3(HID / 32, (2 * N_RNA) / 32), bp, 0, stream>>>(
        W1m, 2 * N_RNA, HID, nullptr, WcatM, 2 * N_RNA, nullptr, nullptr);
    pack32<<<dim3((2 * N_RNA) / 32, HID / 32), bp, 0, stream>>>(
        Wm, HID, 2 * N_RNA, WcatM + (size_t)HID * 2 * N_RNA, nullptr, 0, nullptr, nullptr);
    pack32<<<dim3(HID / 32, HID / 32), bp, 0, stream>>>(
        W2m, HID, HID, nullptr, W2mT, HID, nullptr, nullptr);
    pack32<<<dim3(HID / 32, (2 * N_DIS) / 32), bp, 0, stream>>>(
        W1d, 2 * N_DIS, HID, nullptr, WcatD, 2 * N_DIS, nullptr, nullptr);
    pack32<<<dim3((2 * N_DIS) / 32, HID / 32), bp, 0, stream>>>(
        Wd, HID, 2 * N_DIS, WcatD + (size_t)HID * 2 * N_DIS, nullptr, 0, nullptr, nullptr);
    pack32<<<dim3(HID / 32, HID / 32), bp, 0, stream>>>(
        W2d, HID, HID, nullptr, W2dT, HID, nullptr, nullptr);

    EpiParams ep;

    // ===== m branch =====
    // G1: [6144, 12288] x [12288, 512] -> XwT (bf16) + P2 (fp32)
    ep = {}; ep.mode = 0; ep.TB = XwTm; ep.P2w = P2m; ep.Mld = N_RNA;
    gemm_kern<true><<<dim3(512 / TBN, N_RNA / TBM), 256, 0, stream>>>(
        c_func, c_gs, N_RNA, N_RNA, WcatM, 2 * N_RNA, N_RNA, 512, 2 * N_RNA, ep);
    // G2: edge = Binv * (adj @ Xw) -> edgeT bf16
    ep = {}; ep.mode = 1; ep.deg = degEm; ep.TB = edTm; ep.Mld = N_RNA;
    gemm_kern<false><<<dim3(HID / TBN, N_RNA / TBM), 256, 0, stream>>>(
        adjm, adjm, N_RNA, N_RNA, XwTm, N_RNA, N_RNA, HID, N_RNA, ep);
    // G3: h = relu(Dinv * (adjT @ edge) + b1) -> row-major bf16
    ep = {}; ep.mode = 2; ep.deg = degNm; ep.bias1 = b1m; ep.RB = hm;
    gemm_kern<false><<<dim3(HID / TBN, N_RNA / TBM), 256, 0, stream>>>(
        adjmT, adjmT, N_RNA, N_RNA, edTm, N_RNA, N_RNA, HID, N_RNA, ep);
    // G4: Xw2 = h @ W2 -> Xw2T bf16
    ep = {}; ep.mode = 1; ep.deg = nullptr; ep.TB = Xw2Tm; ep.Mld = N_RNA;
    gemm_kern<false><<<dim3(HID / TBN, N_RNA / TBM), 256, 0, stream>>>(
        hm, hm, HID, HID, W2mT, HID, N_RNA, HID, HID, ep);
    // G5: edge2 = Binv * (adj @ Xw2) -> edge2T bf16
    ep = {}; ep.mode = 1; ep.deg = degEm; ep.TB = ed2Tm; ep.Mld = N_RNA;
    gemm_kern<false><<<dim3(HID / TBN, N_RNA / TBM), 256, 0, stream>>>(
        adjm, adjm, N_RNA, N_RNA, Xw2Tm, N_RNA, N_RNA, HID, N_RNA, ep);
    // G6: out = 0.5*(Dinv*(adjT@edge2) + b2 + P2 + bshort)
    ep = {}; ep.mode = 3; ep.deg = degNm; ep.bias1 = b2m; ep.bias2 = bm;
    ep.P2r = P2m; ep.out = out;
    gemm_kern<false><<<dim3(HID / TBN, N_RNA / TBM), 256, 0, stream>>>(
        adjmT, adjmT, N_RNA, N_RNA, ed2Tm, N_RNA, N_RNA, HID, N_RNA, ep);

    // ===== d branch =====
    ep = {}; ep.mode = 0; ep.TB = XwTd; ep.P2w = P2d; ep.Mld = N_DIS;
    gemm_kern<true><<<dim3(512 / TBN, N_DIS / TBM), 256, 0, stream>>>(
        d_ss, dd_g, N_DIS, N_DIS, WcatD, 2 * N_DIS, N_DIS, 512, 2 * N_DIS, ep);
    ep = {}; ep.mode = 1; ep.deg = degEd; ep.TB = edTd; ep.Mld = N_DIS;
    gemm_kern<false><<<dim3(HID / TBN, N_DIS / TBM), 256, 0, stream>>>(
        adjd, adjd, N_DIS, N_DIS, XwTd, N_DIS, N_DIS, HID, N_DIS, ep);
    ep = {}; ep.mode = 2; ep.deg = degNd; ep.bias1 = b1d; ep.RB = hd;
    gemm_kern<false><<<dim3(HID / TBN, N_DIS / TBM), 256, 0, stream>>>(
        adjdT, adjdT, N_DIS, N_DIS, edTd, N_DIS, N_DIS, HID, N_DIS, ep);
    ep = {}; ep.mode = 1; ep.deg = nullptr; ep.TB = Xw2Td; ep.Mld = N_DIS;
    gemm_kern<false><<<dim3(HID / TBN, N_DIS / TBM), 256, 0, stream>>>(
        hd, hd, HID, HID, W2dT, HID, N_DIS, HID, HID, ep);
    ep = {}; ep.mode = 1; ep.deg = degEd; ep.TB = ed2Td; ep.Mld = N_DIS;
    gemm_kern<false><<<dim3(HID / TBN, N_DIS / TBM), 256, 0, stream>>>(
        adjd, adjd, N_DIS, N_DIS, Xw2Td, N_DIS, N_DIS, HID, N_DIS, ep);
    ep = {}; ep.mode = 3; ep.deg = degNd; ep.bias1 = b2d; ep.bias2 = bd;
    ep.P2r = P2d; ep.out = out + (size_t)N_RNA * HID;
    gemm_kern<false><<<dim3(HID / TBN, N_DIS / TBM), 256, 0, stream>>>(
        adjdT, adjdT, N_DIS, N_DIS, ed2Td, N_DIS, N_DIS, HID, N_DIS, ep);
}

// Round 5
// 1723.541 us; speedup vs baseline: 1.3020x; 1.3020x over previous
//
#include <hip/hip_runtime.h>
#include <hip/hip_bf16.h>
#include <cstddef>

typedef __attribute__((ext_vector_type(8))) short short8;
typedef __attribute__((ext_vector_type(8))) unsigned short u16x8;
typedef __attribute__((ext_vector_type(4))) unsigned short u16x4;
typedef __attribute__((ext_vector_type(4))) float f32x4;

__device__ inline unsigned short f2bf(float f) {
    __hip_bfloat16 h = __float2bfloat16(f);
    unsigned short u;
    __builtin_memcpy(&u, &h, sizeof(u));
    return u;
}

// ---------------------------------------------------------------------------
// Pack / transpose: in fp32 [R,C] -> out bf16 [R,C] and/or outT bf16 [C,R](ldT)
// grid (C/32, R/32), block (32,8)
// ---------------------------------------------------------------------------
__global__ __launch_bounds__(256)
void pack32(const float* __restrict__ in, int R, int C,
            unsigned short* __restrict__ out,
            unsigned short* __restrict__ outT, int ldT)
{
    __shared__ float t[32][33];
    int c0 = blockIdx.x * 32, r0 = blockIdx.y * 32;
    int tx = threadIdx.x, ty = threadIdx.y;
#pragma unroll
    for (int i = 0; i < 4; i++) {
        int r = ty + i * 8;
        float v = in[(size_t)(r0 + r) * C + c0 + tx];
        t[r][tx] = v;
        if (out) out[(size_t)(r0 + r) * C + c0 + tx] = f2bf(v);
    }
    __syncthreads();
    if (outT) {
#pragma unroll
        for (int i = 0; i < 4; i++) {
            int c = ty + i * 8;
            outT[(size_t)(c0 + c) * ldT + r0 + tx] = f2bf(t[tx][c]);
        }
    }
}

// ---------------------------------------------------------------------------
// Sparse build: count nonzeros per row / col.  grid ((C/4)/256, R), block 256.
// ---------------------------------------------------------------------------
__global__ __launch_bounds__(256)
void count_k(const float* __restrict__ A, int C4,
             int* __restrict__ rowcnt, int* __restrict__ colcnt)
{
    int r = blockIdx.y;
    int i = blockIdx.x * 256 + threadIdx.x;
    float4 v = ((const float4*)(A + (size_t)r * C4 * 4))[i];
    int c = i * 4;
    int n = (v.x != 0.f) + (v.y != 0.f) + (v.z != 0.f) + (v.w != 0.f);
    if (n) atomicAdd(&rowcnt[r], n);
    if (v.x != 0.f) atomicAdd(&colcnt[c + 0], 1);
    if (v.y != 0.f) atomicAdd(&colcnt[c + 1], 1);
    if (v.z != 0.f) atomicAdd(&colcnt[c + 2], 1);
    if (v.w != 0.f) atomicAdd(&colcnt[c + 3], 1);
}

// Exclusive scan of cnt[n] -> ptr[0..n] (ptr[n]=total). One block, 1024 thr.
__global__ __launch_bounds__(1024)
void scan_k(const int* __restrict__ cnt, int n, int* __restrict__ ptr)
{
    __shared__ int part[1024];
    int tid = threadIdx.x;
    int chunk = (n + 1023) >> 10;
    int b = tid * chunk, e = b + chunk;
    if (e > n) e = n;
    if (b > n) b = n;
    int s = 0;
    for (int i = b; i < e; ++i) s += cnt[i];
    part[tid] = s;
    __syncthreads();
    for (int off = 1; off < 1024; off <<= 1) {
        int v = (tid >= off) ? part[tid - off] : 0;
        __syncthreads();
        part[tid] += v;
        __syncthreads();
    }
    int run = part[tid] - s;
    for (int i = b; i < e; ++i) { ptr[i] = run; run += cnt[i]; }
    if (tid == 1023) ptr[n] = part[1023];
}

// Fill CSR (row-major) and CSC (col-major) index arrays via atomic cursors.
__global__ __launch_bounds__(256)
void fill_k(const float* __restrict__ A, int C4,
            const int* __restrict__ rowptr, const int* __restrict__ colptr,
            int* __restrict__ rowcur, int* __restrict__ colcur,
            int* __restrict__ rowidx, int* __restrict__ colidx)
{
    int r = blockIdx.y;
    int i = blockIdx.x * 256 + threadIdx.x;
    float4 v = ((const float4*)(A + (size_t)r * C4 * 4))[i];
    int c = i * 4;
    float vv[4] = {v.x, v.y, v.z, v.w};
#pragma unroll
    for (int k = 0; k < 4; k++) {
        if (vv[k] != 0.f) {
            int s1 = atomicAdd(&rowcur[r], 1);
            rowidx[rowptr[r] + s1] = c + k;
            int s2 = atomicAdd(&colcur[c + k], 1);
            colidx[colptr[c + k] + s2] = r;
        }
    }
}

// ---------------------------------------------------------------------------
// SpMM: Y[row,:] = (1/nnz(row)) * sum_{j} X[idx[j], :]   (256 cols fp32)
// one wave per row; block 256 = 4 rows.
// MODE 0: Yf = s*acc                     (fp32)
// MODE 1: Yb = bf16(relu(s*acc + b1))    (bf16)
// MODE 2: out = 0.5*(s*acc + b1 + P2 + b2)
// ---------------------------------------------------------------------------
template<int MODE>
__global__ __launch_bounds__(256)
void spmm_kern(const int* __restrict__ ptr, const int* __restrict__ idx,
               const float* __restrict__ X, int M,
               float* __restrict__ Yf, unsigned short* __restrict__ Yb,
               const float* __restrict__ b1, const float* __restrict__ b2,
               const float* __restrict__ P2, float* __restrict__ out)
{
    int row = blockIdx.x * 4 + (threadIdx.x >> 6);
    if (row >= M) return;
    int lane = threadIdx.x & 63;
    int beg = ptr[row], end = ptr[row + 1];
    f32x4 acc = {0.f, 0.f, 0.f, 0.f};
    int j = beg;
    for (; j + 4 <= end; j += 4) {
        int c0 = idx[j], c1 = idx[j + 1], c2 = idx[j + 2], c3 = idx[j + 3];
        f32x4 v0 = *(const f32x4*)&X[(size_t)c0 * 256 + lane * 4];
        f32x4 v1 = *(const f32x4*)&X[(size_t)c1 * 256 + lane * 4];
        f32x4 v2 = *(const f32x4*)&X[(size_t)c2 * 256 + lane * 4];
        f32x4 v3 = *(const f32x4*)&X[(size_t)c3 * 256 + lane * 4];
        acc += v0 + v1 + v2 + v3;
    }
    for (; j < end; ++j)
        acc += *(const f32x4*)&X[(size_t)idx[j] * 256 + lane * 4];
    float s = (end > beg) ? 1.f / (float)(end - beg) : 0.f;
    size_t o = (size_t)row * 256 + lane * 4;
    if (MODE == 0) {
        *(f32x4*)&Yf[o] = acc * s;
    } else if (MODE == 1) {
        u16x4 hv;
#pragma unroll
        for (int i = 0; i < 4; i++) {
            float h = acc[i] * s + b1[lane * 4 + i];
            hv[i] = f2bf(h > 0.f ? h : 0.f);
        }
        *(u16x4*)&Yb[o] = hv;
    } else {
        f32x4 p = *(const f32x4*)&P2[o];
        f32x4 r;
#pragma unroll
        for (int i = 0; i < 4; i++)
            r[i] = 0.5f * (acc[i] * s + b1[lane * 4 + i] + p[i] + b2[lane * 4 + i]);
        *(f32x4*)&out[o] = r;
    }
}

// ---------------------------------------------------------------------------
// GEMM: C[M,N] = A[M,K] * Bt[N,K]^T   (A fp32 pair (concat on K) or bf16)
// 128x128 tile, BK=32, 256 threads (4 waves 2x2, each 64x64 via 4x4 MFMA)
// MODE 0: n<256 -> out1[m*256+n] fp32 ; n>=256 -> out2[m*256+n-256] fp32
// MODE 1: out1[m*256+n] fp32
// ---------------------------------------------------------------------------
#define TBM 128
#define TBN 128
#define TBK 32
#define LDSK 40

template<bool AF32, int MODE>
__global__ __launch_bounds__(256)
void gemm_kern(const void* __restrict__ Ap1, const void* __restrict__ Ap2,
               int K1, int lda,
               const unsigned short* __restrict__ Bt, int ldb,
               int M, int N, int K,
               float* __restrict__ out1, float* __restrict__ out2)
{
    __shared__ unsigned short Al[TBM][LDSK];
    __shared__ unsigned short Bl[TBN][LDSK];
    int tid = threadIdx.x;
    int l = tid & 63;
    int w = tid >> 6;
    int wr = (w >> 1) * 64;
    int wc = (w & 1) * 64;
    int m0 = blockIdx.y * TBM;
    int n0 = blockIdx.x * TBN;

    f32x4 acc[4][4] = {};

    int srow = tid >> 1, shalf = tid & 1;

    for (int k0 = 0; k0 < K; k0 += TBK) {
        __syncthreads();
        if (AF32) {
            const float* base;
            int kloc;
            if (k0 < K1) { base = (const float*)Ap1; kloc = k0; }
            else         { base = (const float*)Ap2; kloc = k0 - K1; }
            const float* src = base + (size_t)(m0 + srow) * lda + kloc + shalf * 16;
            float4 v0 = ((const float4*)src)[0];
            float4 v1 = ((const float4*)src)[1];
            float4 v2 = ((const float4*)src)[2];
            float4 v3 = ((const float4*)src)[3];
            u16x8 p0, p1;
            p0[0] = f2bf(v0.x); p0[1] = f2bf(v0.y); p0[2] = f2bf(v0.z); p0[3] = f2bf(v0.w);
            p0[4] = f2bf(v1.x); p0[5] = f2bf(v1.y); p0[6] = f2bf(v1.z); p0[7] = f2bf(v1.w);
            p1[0] = f2bf(v2.x); p1[1] = f2bf(v2.y); p1[2] = f2bf(v2.z); p1[3] = f2bf(v2.w);
            p1[4] = f2bf(v3.x); p1[5] = f2bf(v3.y); p1[6] = f2bf(v3.z); p1[7] = f2bf(v3.w);
            *(u16x8*)&Al[srow][shalf * 16]     = p0;
            *(u16x8*)&Al[srow][shalf * 16 + 8] = p1;
        } else {
            const unsigned short* src =
                (const unsigned short*)Ap1 + (size_t)(m0 + srow) * lda + k0 + shalf * 16;
            *(u16x8*)&Al[srow][shalf * 16]     = *(const u16x8*)src;
            *(u16x8*)&Al[srow][shalf * 16 + 8] = *(const u16x8*)(src + 8);
        }
        {
            const unsigned short* src = Bt + (size_t)(n0 + srow) * ldb + k0 + shalf * 16;
            *(u16x8*)&Bl[srow][shalf * 16]     = *(const u16x8*)src;
            *(u16x8*)&Bl[srow][shalf * 16 + 8] = *(const u16x8*)(src + 8);
        }
        __syncthreads();
        short8 af[4], bfr[4];
        int ko = (l >> 4) * 8;
        int ar = l & 15;
#pragma unroll
        for (int fi = 0; fi < 4; fi++)
            af[fi] = *(const short8*)&Al[wr + fi * 16 + ar][ko];
#pragma unroll
        for (int fj = 0; fj < 4; fj++)
            bfr[fj] = *(const short8*)&Bl[wc + fj * 16 + ar][ko];
#pragma unroll
        for (int fi = 0; fi < 4; fi++)
#pragma unroll
            for (int fj = 0; fj < 4; fj++)
                acc[fi][fj] = __builtin_amdgcn_mfma_f32_16x16x32_bf16(
                    af[fi], bfr[fj], acc[fi][fj], 0, 0, 0);
    }

#pragma unroll
    for (int fi = 0; fi < 4; fi++) {
#pragma unroll
        for (int fj = 0; fj < 4; fj++) {
#pragma unroll
            for (int r = 0; r < 4; r++) {
                int m = m0 + wr + fi * 16 + ((l >> 4) << 2) + r;
                int n = n0 + wc + fj * 16 + (l & 15);
                float v = acc[fi][fj][r];
                if (MODE == 0) {
                    if (n < 256) out1[(size_t)m * 256 + n] = v;
                    else         out2[(size_t)m * 256 + (n - 256)] = v;
                } else {
                    out1[(size_t)m * 256 + n] = v;
                }
            }
        }
    }
}

// ---------------------------------------------------------------------------
#define N_RNA 6144
#define N_DIS 4096
#define HID 256

extern "C" void kernel_launch(void* const* d_in, const int* in_sizes, int n_in,
                              void* d_out, int out_size, void* d_ws, size_t ws_size,
                              hipStream_t stream) {
    const float* m_f   = (const float*)d_in[0];
    const float* d_f   = (const float*)d_in[1];
    const float* c_func= (const float*)d_in[2];
    const float* c_gs  = (const float*)d_in[3];
    const float* d_ss  = (const float*)d_in[4];
    const float* dd_g  = (const float*)d_in[5];
    const float* W1m   = (const float*)d_in[6];
    const float* b1m   = (const float*)d_in[7];
    const float* W2m   = (const float*)d_in[8];
    const float* b2m   = (const float*)d_in[9];
    const float* W1d   = (const float*)d_in[10];
    const float* b1d   = (const float*)d_in[11];
    const float* W2d   = (const float*)d_in[12];
    const float* b2d   = (const float*)d_in[13];
    const float* Wm    = (const float*)d_in[14];
    const float* bm    = (const float*)d_in[15];
    const float* Wd    = (const float*)d_in[16];
    const float* bd    = (const float*)d_in[17];
    float* out = (float*)d_out;

    char* ws = (char*)d_ws;
    size_t off = 0;
    auto alloc = [&](size_t bytes) {
        void* p = ws + off;
        off = (off + bytes + 255) & ~(size_t)255;
        return p;
    };

    // zeroed int region: counts + cursors (m: 4x6144, d: 4x4096)
    int* zint = (int*)alloc((size_t)(4 * N_RNA + 4 * N_DIS) * 4);
    int* rcnt_m = zint;
    int* ccnt_m = zint + N_RNA;
    int* rcur_m = zint + 2 * N_RNA;
    int* ccur_m = zint + 3 * N_RNA;
    int* rcnt_d = zint + 4 * N_RNA;
    int* ccnt_d = zint + 4 * N_RNA + N_DIS;
    int* rcur_d = zint + 4 * N_RNA + 2 * N_DIS;
    int* ccur_d = zint + 4 * N_RNA + 3 * N_DIS;

    int* rptr_m = (int*)alloc((size_t)(N_RNA + 1) * 4);
    int* cptr_m = (int*)alloc((size_t)(N_RNA + 1) * 4);
    int* rptr_d = (int*)alloc((size_t)(N_DIS + 1) * 4);
    int* cptr_d = (int*)alloc((size_t)(N_DIS + 1) * 4);
    const int CAP_M = 786432, CAP_D = 393216;  // ~2x expected nnz
    int* ridx_m = (int*)alloc((size_t)CAP_M * 4);
    int* cidx_m = (int*)alloc((size_t)CAP_M * 4);
    int* ridx_d = (int*)alloc((size_t)CAP_D * 4);
    int* cidx_d = (int*)alloc((size_t)CAP_D * 4);

    unsigned short* WcatM = (unsigned short*)alloc((size_t)512 * 2 * N_RNA * 2);
    unsigned short* WcatD = (unsigned short*)alloc((size_t)512 * 2 * N_DIS * 2);
    unsigned short* W2mT  = (unsigned short*)alloc((size_t)HID * HID * 2);
    unsigned short* W2dT  = (unsigned short*)alloc((size_t)HID * HID * 2);

    float* Xwm  = (float*)alloc((size_t)N_RNA * HID * 4);
    float* P2m  = (float*)alloc((size_t)N_RNA * HID * 4);
    float* edgm = (float*)alloc((size_t)N_RNA * HID * 4);
    float* Xw2m = (float*)alloc((size_t)N_RNA * HID * 4);
    unsigned short* hm = (unsigned short*)alloc((size_t)N_RNA * HID * 2);
    float* Xwd  = (float*)alloc((size_t)N_DIS * HID * 4);
    float* P2d  = (float*)alloc((size_t)N_DIS * HID * 4);
    float* edgd = (float*)alloc((size_t)N_DIS * HID * 4);
    float* Xw2d = (float*)alloc((size_t)N_DIS * HID * 4);
    unsigned short* hd = (unsigned short*)alloc((size_t)N_DIS * HID * 2);

    hipMemsetAsync(zint, 0, (size_t)(4 * N_RNA + 4 * N_DIS) * 4, stream);

    dim3 bp(32, 8);
    // weights: WcatM rows 0..255 = W1m^T, rows 256..511 = Wm (both [*, 2N] bf16)
    pack32<<<dim3(HID / 32, (2 * N_RNA) / 32), bp, 0, stream>>>(
        W1m, 2 * N_RNA, HID, nullptr, WcatM, 2 * N_RNA);
    pack32<<<dim3((2 * N_RNA) / 32, HID / 32), bp, 0, stream>>>(
        Wm, HID, 2 * N_RNA, WcatM + (size_t)HID * 2 * N_RNA, nullptr, 0);
    pack32<<<dim3(HID / 32, HID / 32), bp, 0, stream>>>(
        W2m, HID, HID, nullptr, W2mT, HID);
    pack32<<<dim3(HID / 32, (2 * N_DIS) / 32), bp, 0, stream>>>(
        W1d, 2 * N_DIS, HID, nullptr, WcatD, 2 * N_DIS);
    pack32<<<dim3((2 * N_DIS) / 32, HID / 32), bp, 0, stream>>>(
        Wd, HID, 2 * N_DIS, WcatD + (size_t)HID * 2 * N_DIS, nullptr, 0);
    pack32<<<dim3(HID / 32, HID / 32), bp, 0, stream>>>(
        W2d, HID, HID, nullptr, W2dT, HID);

    // sparse build
    count_k<<<dim3((N_RNA / 4) / 256, N_RNA), 256, 0, stream>>>(m_f, N_RNA / 4, rcnt_m, ccnt_m);
    count_k<<<dim3((N_DIS / 4) / 256, N_DIS), 256, 0, stream>>>(d_f, N_DIS / 4, rcnt_d, ccnt_d);
    scan_k<<<1, 1024, 0, stream>>>(rcnt_m, N_RNA, rptr_m);
    scan_k<<<1, 1024, 0, stream>>>(ccnt_m, N_RNA, cptr_m);
    scan_k<<<1, 1024, 0, stream>>>(rcnt_d, N_DIS, rptr_d);
    scan_k<<<1, 1024, 0, stream>>>(ccnt_d, N_DIS, cptr_d);
    fill_k<<<dim3((N_RNA / 4) / 256, N_RNA), 256, 0, stream>>>(
        m_f, N_RNA / 4, rptr_m, cptr_m, rcur_m, ccur_m, ridx_m, cidx_m);
    fill_k<<<dim3((N_DIS / 4) / 256, N_DIS), 256, 0, stream>>>(
        d_f, N_DIS / 4, rptr_d, cptr_d, rcur_d, ccur_d, ridx_d, cidx_d);

    // G1: features -> Xw (fp32) + P2 (fp32)
    gemm_kern<true, 0><<<dim3(512 / TBN, N_RNA / TBM), 256, 0, stream>>>(
        c_func, c_gs, N_RNA, N_RNA, WcatM, 2 * N_RNA, N_RNA, 512, 2 * N_RNA, Xwm, P2m);
    gemm_kern<true, 0><<<dim3(512 / TBN, N_DIS / TBM), 256, 0, stream>>>(
        d_ss, dd_g, N_DIS, N_DIS, WcatD, 2 * N_DIS, N_DIS, 512, 2 * N_DIS, Xwd, P2d);

    // ===== m branch sparse pipeline =====
    spmm_kern<0><<<N_RNA / 4, 256, 0, stream>>>(
        rptr_m, ridx_m, Xwm, N_RNA, edgm, nullptr, nullptr, nullptr, nullptr, nullptr);
    spmm_kern<1><<<N_RNA / 4, 256, 0, stream>>>(
        cptr_m, cidx_m, edgm, N_RNA, nullptr, hm, b1m, nullptr, nullptr, nullptr);
    gemm_kern<false, 1><<<dim3(HID / TBN, N_RNA / TBM), 256, 0, stream>>>(
        hm, hm, HID, HID, W2mT, HID, N_RNA, HID, HID, Xw2m, nullptr);
    spmm_kern<0><<<N_RNA / 4, 256, 0, stream>>>(
        rptr_m, ridx_m, Xw2m, N_RNA, edgm, nullptr, nullptr, nullptr, nullptr, nullptr);
    spmm_kern<2><<<N_RNA / 4, 256, 0, stream>>>(
        cptr_m, cidx_m, edgm, N_RNA, nullptr, nullptr, b2m, bm, P2m, out);

    // ===== d branch sparse pipeline =====
    spmm_kern<0><<<N_DIS / 4, 256, 0, stream>>>(
        rptr_d, ridx_d, Xwd, N_DIS, edgd, nullptr, nullptr, nullptr, nullptr, nullptr);
    spmm_kern<1><<<N_DIS / 4, 256, 0, stream>>>(
        cptr_d, cidx_d, edgd, N_DIS, nullptr, hd, b1d, nullptr, nullptr, nullptr);
    gemm_kern<false, 1><<<dim3(HID / TBN, N_DIS / TBM), 256, 0, stream>>>(
        hd, hd, HID, HID, W2dT, HID, N_DIS, HID, HID, Xw2d, nullptr);
    spmm_kern<0><<<N_DIS / 4, 256, 0, stream>>>(
        rptr_d, ridx_d, Xw2d, N_DIS, edgd, nullptr, nullptr, nullptr, nullptr, nullptr);
    spmm_kern<2><<<N_DIS / 4, 256, 0, stream>>>(
        cptr_d, cidx_d, edgd, N_DIS, nullptr, nullptr, b2d, bd, P2d,
        out + (size_t)N_RNA * HID);
}